// Round 10
// baseline (135.038 us; speedup 1.0000x reference)
//
#include <hip/hip_runtime.h>
#include <hip/hip_bf16.h>
#include <stdint.h>

#define Bdim 32
#define Tdim 128
#define Fdim 2048
#define Mdim (Bdim*Tdim)   // 4096

#define BM 256
#define BN 128
#define BK 64
#define NT (Fdim/BK)       // 32

typedef __attribute__((ext_vector_type(8))) short bf16x8;
typedef __attribute__((ext_vector_type(4))) float f32x4;

__device__ inline unsigned short f2bf(float f) {
    union { float f; unsigned u; } x; x.f = f;
    unsigned r = (x.u + 0x7fffu + ((x.u >> 16) & 1u)) >> 16;   // RNE
    return (unsigned short)r;
}

// ---------------- kernel 1: fp32 -> bf16 convert (input and W) ----------------
__global__ void convert_kernel(const float* __restrict__ A, const float* __restrict__ W,
                               unsigned short* __restrict__ a16, unsigned short* __restrict__ w16) {
    const int nA4 = (Mdim * Fdim) / 4;   // 2097152
    const int nW4 = (Fdim * Fdim) / 4;   // 1048576
    const int stride = gridDim.x * blockDim.x;
    for (int i = blockIdx.x * blockDim.x + threadIdx.x; i < nA4 + nW4; i += stride) {
        const float4* src; unsigned short* dst; int j;
        if (i < nA4) { src = (const float4*)A; dst = a16; j = i; }
        else         { src = (const float4*)W; dst = w16; j = i - nA4; }
        float4 v = src[j];
        ushort4 o;
        o.x = f2bf(v.x); o.y = f2bf(v.y); o.z = f2bf(v.z); o.w = f2bf(v.w);
        *(ushort4*)(dst + 4 * (size_t)j) = o;
    }
}

// ------- kernel 2: 256x128 bf16 GEMM, tri-buffer dist-2 counted-vmcnt (T4) +
//         2-phase-per-K-step interleave w/ setprio (T3+T5) + 0-conflict swizzle (T2)
//         + fused LIF epilogue.
// 512 threads = 8 waves (4M x 2N, 64x64 out each). Grid 16x16 = 256 = 1 block/CU.
// Per K-step t (buf t%3): phase kk=0: {vmcnt(6); barrier; 3 stage-loads(t+2);
// 8 ds_read; lgkmcnt(0); setprio(1); 16 MFMA; setprio(0)} then phase kk=1 same with
// a leading barrier. vmcnt ledger: steady state 12 outstanding -> wait to 6 (=stage(t+1)
// stays in flight); t=NT-1 peels to 0. stage(t+2) writes buf (t-1)%3, proven read-done
// at the phase-A barrier (all waves issued lgkmcnt(0) before their phase-B MFMAs).
__global__ __launch_bounds__(512, 2) void gemm_fused_kernel(const unsigned short* __restrict__ A,
                                                            const unsigned short* __restrict__ Wm,
                                                            const float* __restrict__ bias,
                                                            float* __restrict__ Z) {
    __shared__ __align__(16) char smem[147456];   // max(3*49152, 256*132*4)

    const int tid = threadIdx.x;
    const int wid = tid >> 6, lane = tid & 63;
    const int wr = wid >> 1, wc = wid & 1;          // wave -> 64x64 sub-tile of 256x128
    const int m0 = blockIdx.y * BM, n0 = blockIdx.x * BN;

    f32x4 acc[4][4];
#pragma unroll
    for (int i = 0; i < 4; i++)
#pragma unroll
        for (int j = 0; j < 4; j++) acc[i][j] = f32x4{0.f, 0.f, 0.f, 0.f};

    const int frow = lane & 15;
    const int lgrp = lane >> 4;                     // 0..3: k-slot group

    // swizzle (R6-verified 0 conflicts): row = 8 chunks of 16B; data chunk c of row r
    // stored at slot c^(r&7). LDS dest LINEAR (global_load_lds reqt), source pre-permuted.
    // Full stage = 6 gload_lds/wave (4 A + 2 B), split 3+3 across the two phases.
    auto stageA = [&](int buf, int kt) {            // A chunks j=0..2
        const int k0 = kt * BK;
        char* sAb = smem + buf * 49152;
#pragma unroll
        for (int j = 0; j < 3; ++j) {
            const int base = wid * 4096 + j * 1024;
            const int off  = base + lane * 16;
            const int row  = off >> 7;
            const int chk  = (off & 127) >> 4;
            const int scol = (chk ^ (row & 7)) << 3;
            const unsigned short* ga = A + (size_t)(m0 + row) * Fdim + k0 + scol;
            __builtin_amdgcn_global_load_lds(
                (const __attribute__((address_space(1))) void*)ga,
                (__attribute__((address_space(3))) void*)(sAb + base), 16, 0, 0);
        }
    };
    auto stageB = [&](int buf, int kt) {            // A chunk j=3 + B chunks j=0..1
        const int k0 = kt * BK;
        char* sAb = smem + buf * 49152;
        char* sBb = sAb + 32768;
        {
            const int base = wid * 4096 + 3 * 1024;
            const int off  = base + lane * 16;
            const int row  = off >> 7;
            const int chk  = (off & 127) >> 4;
            const int scol = (chk ^ (row & 7)) << 3;
            const unsigned short* ga = A + (size_t)(m0 + row) * Fdim + k0 + scol;
            __builtin_amdgcn_global_load_lds(
                (const __attribute__((address_space(1))) void*)ga,
                (__attribute__((address_space(3))) void*)(sAb + base), 16, 0, 0);
        }
#pragma unroll
        for (int j = 0; j < 2; ++j) {
            const int base = wid * 2048 + j * 1024;
            const int off  = base + lane * 16;
            const int row  = off >> 7;
            const int chk  = (off & 127) >> 4;
            const int scol = (chk ^ (row & 7)) << 3;
            const unsigned short* gb = Wm + (size_t)(n0 + row) * Fdim + k0 + scol;
            __builtin_amdgcn_global_load_lds(
                (const __attribute__((address_space(1))) void*)gb,
                (__attribute__((address_space(3))) void*)(sBb + base), 16, 0, 0);
        }
    };

    stageA(0, 0); stageB(0, 0);
    stageA(1, 1); stageB(1, 1);

#pragma unroll 1
    for (int t = 0; t < NT; ++t) {
        const unsigned short* sAc = (const unsigned short*)(smem + (t % 3) * 49152);
        const unsigned short* sBc = (const unsigned short*)(smem + (t % 3) * 49152 + 32768);

        // ---- phase A (kk = 0) ----
        if (t < NT - 1) asm volatile("s_waitcnt vmcnt(6)" ::: "memory");
        else            asm volatile("s_waitcnt vmcnt(0)" ::: "memory");
        __builtin_amdgcn_s_barrier();
        __builtin_amdgcn_sched_barrier(0);
        if (t + 2 < NT) stageA((t + 2) % 3, t + 2);

        bf16x8 af[4], bfr[4];
#pragma unroll
        for (int mi = 0; mi < 4; mi++) {
            const int r = wr * 64 + mi * 16 + frow;
            af[mi] = *(const bf16x8*)(sAc + r * BK + (((lgrp) ^ (r & 7)) << 3));
        }
#pragma unroll
        for (int ni = 0; ni < 4; ni++) {
            const int r = wc * 64 + ni * 16 + frow;
            bfr[ni] = *(const bf16x8*)(sBc + r * BK + (((lgrp) ^ (r & 7)) << 3));
        }
        asm volatile("s_waitcnt lgkmcnt(0)" ::: "memory");
        __builtin_amdgcn_sched_barrier(0);
        __builtin_amdgcn_s_setprio(1);
#pragma unroll
        for (int mi = 0; mi < 4; mi++)
#pragma unroll
            for (int ni = 0; ni < 4; ni++)
                acc[mi][ni] = __builtin_amdgcn_mfma_f32_16x16x32_bf16(af[mi], bfr[ni], acc[mi][ni], 0, 0, 0);
        __builtin_amdgcn_s_setprio(0);

        // ---- phase B (kk = 1) ----
        __builtin_amdgcn_s_barrier();
        __builtin_amdgcn_sched_barrier(0);
        if (t + 2 < NT) stageB((t + 2) % 3, t + 2);

#pragma unroll
        for (int mi = 0; mi < 4; mi++) {
            const int r = wr * 64 + mi * 16 + frow;
            af[mi] = *(const bf16x8*)(sAc + r * BK + (((4 + lgrp) ^ (r & 7)) << 3));
        }
#pragma unroll
        for (int ni = 0; ni < 4; ni++) {
            const int r = wc * 64 + ni * 16 + frow;
            bfr[ni] = *(const bf16x8*)(sBc + r * BK + (((4 + lgrp) ^ (r & 7)) << 3));
        }
        asm volatile("s_waitcnt lgkmcnt(0)" ::: "memory");
        __builtin_amdgcn_sched_barrier(0);
        __builtin_amdgcn_s_setprio(1);
#pragma unroll
        for (int mi = 0; mi < 4; mi++)
#pragma unroll
            for (int ni = 0; ni < 4; ni++)
                acc[mi][ni] = __builtin_amdgcn_mfma_f32_16x16x32_bf16(af[mi], bfr[ni], acc[mi][ni], 0, 0, 0);
        __builtin_amdgcn_s_setprio(0);
    }

    __syncthreads();   // full drain; all waves done with staging buffers

    // ---- fused LIF epilogue ----
    // acc -> ctile[256][132] f32 (pad 132: 4-row groups land 16 banks apart -> 2-way free)
    float* ct = (float*)smem;
#pragma unroll
    for (int mi = 0; mi < 4; mi++)
#pragma unroll
        for (int ni = 0; ni < 4; ni++) {
            const int r0 = wr * 64 + mi * 16 + (lane >> 4) * 4;
            const int c0 = wc * 64 + ni * 16 + (lane & 15);
#pragma unroll
            for (int r = 0; r < 4; r++) ct[(r0 + r) * 132 + c0] = acc[mi][ni][r];
        }
    __syncthreads();

    // rows m0..m0+255 = batches 2*by, 2*by+1 (t = row & 127). 256 scan chains, tid<256.
    if (tid < 256) {
        const int sub  = tid >> 7;                   // which of the 2 batches in this tile
        const int col  = tid & 127;
        const int gcol = n0 + col;
        const float bf = bias[gcol];
        float* outp = Z + (size_t)(m0 + sub * 128) * Fdim + gcol;
        float v = 0.f;
#pragma unroll 16
        for (int t = 0; t < Tdim; t++) {
            const float g = ct[(sub * 128 + t) * 132 + col] + bf;
            const float vn = v + 0.01f * ((0.0f - v) + g);
            const float z = (vn > 1.0f) ? 1.0f : 0.0f;
            v = vn - z;                    // subtractive reset (V_TH = 1)
            outp[(size_t)t * Fdim] = z;
        }
    }
}

// ---------------- fallback fp32 GEMM (only if ws too small; insurance) ----------------
__global__ void gemm_f32_naive(const float* __restrict__ A, const float* __restrict__ W,
                               float* __restrict__ C) {
    int col = blockIdx.x * blockDim.x + threadIdx.x;
    int row = blockIdx.y;
    float s = 0.f;
    for (int k = 0; k < Fdim; k++) s += A[(size_t)row * Fdim + k] * W[(size_t)col * Fdim + k];
    C[(size_t)row * Fdim + col] = s;
}

// ---------------- fallback LIF scan (only used with gemm_f32_naive path) --------------
__global__ __launch_bounds__(256, 1) void lif_kernel(float* __restrict__ gs,
                                                     const float* __restrict__ bias) {
    int idx = blockIdx.x * blockDim.x + threadIdx.x;   // b*F + f
    int b = idx >> 11, f = idx & (Fdim - 1);
    const float bf = bias[f];
    float* p = gs + (size_t)b * Tdim * Fdim + f;
    float v = 0.f;
#pragma unroll 16
    for (int t = 0; t < Tdim; t++) {
        float g = p[(size_t)t * Fdim] + bf;
        float vn = v + 0.01f * ((0.0f - v) + g);
        float z = (vn > 1.0f) ? 1.0f : 0.0f;
        v = vn - z;
        p[(size_t)t * Fdim] = z;
    }
}

extern "C" void kernel_launch(void* const* d_in, const int* in_sizes, int n_in,
                              void* d_out, int out_size, void* d_ws, size_t ws_size,
                              hipStream_t stream) {
    const float* inp  = (const float*)d_in[0];
    const float* W    = (const float*)d_in[1];
    const float* bias = (const float*)d_in[2];
    float* out = (float*)d_out;

    const size_t needA = (size_t)Mdim * Fdim * 2;   // 16.8 MB
    const size_t needW = (size_t)Fdim * Fdim * 2;   //  8.4 MB

    if (ws_size >= needA + needW) {
        unsigned short* a16 = (unsigned short*)d_ws;
        unsigned short* w16 = (unsigned short*)((char*)d_ws + needA);
        convert_kernel<<<2048, 256, 0, stream>>>(inp, W, a16, w16);
        dim3 grid(Fdim / BN, Mdim / BM);            // (16, 16) = 256 blocks = 1/CU
        gemm_fused_kernel<<<grid, 512, 0, stream>>>(a16, w16, bias, out);
    } else {
        dim3 grid(Fdim / 256, Mdim);
        gemm_f32_naive<<<grid, 256, 0, stream>>>(inp, W, out);
        lif_kernel<<<(Bdim * Fdim) / 256, 256, 0, stream>>>(out, bias);
    }
}

// Round 12
// 132.739 us; speedup vs baseline: 1.0173x; 1.0173x over previous
//
#include <hip/hip_runtime.h>
#include <hip/hip_bf16.h>
#include <stdint.h>

#define Bdim 32
#define Tdim 128
#define Fdim 2048
#define Mdim (Bdim*Tdim)   // 4096

#define BM 256
#define BN 128
#define BK 64
#define NT (Fdim/BK)       // 32

typedef __attribute__((ext_vector_type(8))) short bf16x8;
typedef __attribute__((ext_vector_type(4))) float f32x4;

__device__ inline unsigned short f2bf(float f) {
    union { float f; unsigned u; } x; x.f = f;
    unsigned r = (x.u + 0x7fffu + ((x.u >> 16) & 1u)) >> 16;   // RNE
    return (unsigned short)r;
}

// ---------------- kernel 1: fp32 -> bf16 convert (input and W) ----------------
__global__ void convert_kernel(const float* __restrict__ A, const float* __restrict__ W,
                               unsigned short* __restrict__ a16, unsigned short* __restrict__ w16) {
    const int nA4 = (Mdim * Fdim) / 4;   // 2097152
    const int nW4 = (Fdim * Fdim) / 4;   // 1048576
    const int stride = gridDim.x * blockDim.x;
    for (int i = blockIdx.x * blockDim.x + threadIdx.x; i < nA4 + nW4; i += stride) {
        const float4* src; unsigned short* dst; int j;
        if (i < nA4) { src = (const float4*)A; dst = a16; j = i; }
        else         { src = (const float4*)W; dst = w16; j = i - nA4; }
        float4 v = src[j];
        ushort4 o;
        o.x = f2bf(v.x); o.y = f2bf(v.y); o.z = f2bf(v.z); o.w = f2bf(v.w);
        *(ushort4*)(dst + 4 * (size_t)j) = o;
    }
}

// ------- kernel 2: 256x128 bf16 GEMM (R9 loop: tri-buffer dist-2 counted-vmcnt +
//         0-conflict swizzle) + T1 XCD-chunked block swizzle + fused LIF epilogue ----
// 512 threads = 8 waves (4M x 2N, 64x64 out each). Grid 256 (1-D) = 1 block/CU.
// XCD swizzle: XCD k = wg&7 owns a 4(by) x 8(bx) contiguous sub-grid -> per-K-step
// distinct-tile L2-miss traffic drops 544->256 KB/XCD (L3-BW relief theory).
__global__ __launch_bounds__(512, 2) void gemm_fused_kernel(const unsigned short* __restrict__ A,
                                                            const unsigned short* __restrict__ Wm,
                                                            const float* __restrict__ bias,
                                                            float* __restrict__ Z) {
    __shared__ __align__(16) char smem[147456];   // max(3*49152, 256*132*4)

    const int tid = threadIdx.x;
    const int wid = tid >> 6, lane = tid & 63;
    const int wr = wid >> 1, wc = wid & 1;          // wave -> 64x64 sub-tile of 256x128
    // XCD-chunked bijective remap (grid 256 = 8 XCD x 32, dispatch round-robins wg%8)
    const int wg  = blockIdx.x;
    const int xcd = wg & 7, idx = wg >> 3;          // idx in [0,32)
    const int by  = (xcd >> 1) * 4 + (idx >> 3);    // 4 consecutive M-rows per XCD
    const int bx  = (xcd & 1) * 8 + (idx & 7);      // 8 consecutive N-cols per XCD
    const int m0 = by * BM, n0 = bx * BN;

    f32x4 acc[4][4];
#pragma unroll
    for (int i = 0; i < 4; i++)
#pragma unroll
        for (int j = 0; j < 4; j++) acc[i][j] = f32x4{0.f, 0.f, 0.f, 0.f};

    const int frow = lane & 15;
    const int lgrp = lane >> 4;                     // 0..3: k-slot group

    // swizzle (R6-verified 0 conflicts): row = 8 chunks of 16B; data chunk c of row r
    // stored at slot c^(r&7). LDS dest LINEAR (global_load_lds reqt), source pre-permuted.
    // 6 global_load_lds per wave per stage (4 A + 2 B) -> vmcnt counts in units of 6.
    auto stage = [&](int buf, int kt) {
        const int k0 = kt * BK;
        char* sAb = smem + buf * 49152;
        char* sBb = sAb + 32768;
#pragma unroll
        for (int j = 0; j < 4; ++j) {                 // A: 32KB = 32 chunks, 4/wave
            const int base = wid * 4096 + j * 1024;
            const int off  = base + lane * 16;
            const int row  = off >> 7;                // 128B per tile row (0..255)
            const int chk  = (off & 127) >> 4;
            const int scol = (chk ^ (row & 7)) << 3;
            const unsigned short* ga = A + (size_t)(m0 + row) * Fdim + k0 + scol;
            __builtin_amdgcn_global_load_lds(
                (const __attribute__((address_space(1))) void*)ga,
                (__attribute__((address_space(3))) void*)(sAb + base), 16, 0, 0);
        }
#pragma unroll
        for (int j = 0; j < 2; ++j) {                 // B: 16KB = 16 chunks, 2/wave
            const int base = wid * 2048 + j * 1024;
            const int off  = base + lane * 16;
            const int row  = off >> 7;                // 0..127
            const int chk  = (off & 127) >> 4;
            const int scol = (chk ^ (row & 7)) << 3;
            const unsigned short* gb = Wm + (size_t)(n0 + row) * Fdim + k0 + scol;
            __builtin_amdgcn_global_load_lds(
                (const __attribute__((address_space(1))) void*)gb,
                (__attribute__((address_space(3))) void*)(sBb + base), 16, 0, 0);
        }
    };

    stage(0, 0);
    stage(1, 1);

#pragma unroll 1
    for (int t = 0; t < NT; ++t) {
        if (t < NT - 1) asm volatile("s_waitcnt vmcnt(6)" ::: "memory");
        else            asm volatile("s_waitcnt vmcnt(0)" ::: "memory");
        __builtin_amdgcn_s_barrier();
        __builtin_amdgcn_sched_barrier(0);            // nothing hoists above the barrier
        if (t + 2 < NT) stage((t + 2) % 3, t + 2);

        const unsigned short* sAc = (const unsigned short*)(smem + (t % 3) * 49152);
        const unsigned short* sBc = (const unsigned short*)(smem + (t % 3) * 49152 + 32768);
        bf16x8 af[2][4], bfr[2][4];
#pragma unroll
        for (int kk = 0; kk < 2; kk++) {
            const int chunk = kk * 4 + lgrp;
#pragma unroll
            for (int mi = 0; mi < 4; mi++) {
                const int r = wr * 64 + mi * 16 + frow;
                af[kk][mi] = *(const bf16x8*)(sAc + r * BK + ((chunk ^ (r & 7)) << 3));
            }
#pragma unroll
            for (int ni = 0; ni < 4; ni++) {
                const int r = wc * 64 + ni * 16 + frow;
                bfr[kk][ni] = *(const bf16x8*)(sBc + r * BK + ((chunk ^ (r & 7)) << 3));
            }
        }
#pragma unroll
        for (int kk = 0; kk < 2; kk++)
#pragma unroll
            for (int mi = 0; mi < 4; mi++)
#pragma unroll
                for (int ni = 0; ni < 4; ni++)
                    acc[mi][ni] = __builtin_amdgcn_mfma_f32_16x16x32_bf16(af[kk][mi], bfr[kk][ni], acc[mi][ni], 0, 0, 0);
    }

    __syncthreads();   // full drain; all waves done with staging buffers

    // ---- fused LIF epilogue ----
    // acc -> ctile[256][132] f32 (pad 132: 4-row groups land 16 banks apart -> 2-way free)
    float* ct = (float*)smem;
#pragma unroll
    for (int mi = 0; mi < 4; mi++)
#pragma unroll
        for (int ni = 0; ni < 4; ni++) {
            const int r0 = wr * 64 + mi * 16 + (lane >> 4) * 4;
            const int c0 = wc * 64 + ni * 16 + (lane & 15);
#pragma unroll
            for (int r = 0; r < 4; r++) ct[(r0 + r) * 132 + c0] = acc[mi][ni][r];
        }
    __syncthreads();

    // rows m0..m0+255 = batches 2*by, 2*by+1 (t = row & 127). 256 scan chains, tid<256.
    if (tid < 256) {
        const int sub  = tid >> 7;                   // which of the 2 batches in this tile
        const int col  = tid & 127;
        const int gcol = n0 + col;
        const float bf = bias[gcol];
        float* outp = Z + (size_t)(m0 + sub * 128) * Fdim + gcol;
        float v = 0.f;
#pragma unroll 16
        for (int t = 0; t < Tdim; t++) {
            const float g = ct[(sub * 128 + t) * 132 + col] + bf;
            const float vn = v + 0.01f * ((0.0f - v) + g);
            const float z = (vn > 1.0f) ? 1.0f : 0.0f;
            v = vn - z;                    // subtractive reset (V_TH = 1)
            outp[(size_t)t * Fdim] = z;
        }
    }
}

// ---------------- fallback fp32 GEMM (only if ws too small; insurance) ----------------
__global__ void gemm_f32_naive(const float* __restrict__ A, const float* __restrict__ W,
                               float* __restrict__ C) {
    int col = blockIdx.x * blockDim.x + threadIdx.x;
    int row = blockIdx.y;
    float s = 0.f;
    for (int k = 0; k < Fdim; k++) s += A[(size_t)row * Fdim + k] * W[(size_t)col * Fdim + k];
    C[(size_t)row * Fdim + col] = s;
}

// ---------------- fallback LIF scan (only used with gemm_f32_naive path) --------------
__global__ __launch_bounds__(256, 1) void lif_kernel(float* __restrict__ gs,
                                                     const float* __restrict__ bias) {
    int idx = blockIdx.x * blockDim.x + threadIdx.x;   // b*F + f
    int b = idx >> 11, f = idx & (Fdim - 1);
    const float bf = bias[f];
    float* p = gs + (size_t)b * Tdim * Fdim + f;
    float v = 0.f;
#pragma unroll 16
    for (int t = 0; t < Tdim; t++) {
        float g = p[(size_t)t * Fdim] + bf;
        float vn = v + 0.01f * ((0.0f - v) + g);
        float z = (vn > 1.0f) ? 1.0f : 0.0f;
        v = vn - z;
        p[(size_t)t * Fdim] = z;
    }
}

extern "C" void kernel_launch(void* const* d_in, const int* in_sizes, int n_in,
                              void* d_out, int out_size, void* d_ws, size_t ws_size,
                              hipStream_t stream) {
    const float* inp  = (const float*)d_in[0];
    const float* W    = (const float*)d_in[1];
    const float* bias = (const float*)d_in[2];
    float* out = (float*)d_out;

    const size_t needA = (size_t)Mdim * Fdim * 2;   // 16.8 MB
    const size_t needW = (size_t)Fdim * Fdim * 2;   //  8.4 MB

    if (ws_size >= needA + needW) {
        unsigned short* a16 = (unsigned short*)d_ws;
        unsigned short* w16 = (unsigned short*)((char*)d_ws + needA);
        convert_kernel<<<2048, 256, 0, stream>>>(inp, W, a16, w16);
        gemm_fused_kernel<<<dim3(256), 512, 0, stream>>>(a16, w16, bias, out);
    } else {
        dim3 grid(Fdim / 256, Mdim);
        gemm_f32_naive<<<grid, 256, 0, stream>>>(inp, W, out);
        lif_kernel<<<(Bdim * Fdim) / 256, 256, 0, stream>>>(out, bias);
    }
}